// Round 10
// baseline (862.746 us; speedup 1.0000x reference)
//
#include <hip/hip_runtime.h>
#include <math.h>

// GRU C=64, L=2, B=2048, SEQ=512, DEC=35. BT=4 rows/block, grid=512
// -> 2 BLOCKS PER CU so one block's compute fills the other's barrier/latency
// holes (round-8 showed 1 block/CU is latency/barrier-bound: all pipes <55%).
//
// LANE-LOCAL CELL (as round 8): per phase G[gate][b] = [Wih|Whh](K=128).[x;h]
// via MFMA with weights as A operand (VGPR-resident bf16 all kernel), staged
// activations as B. Padded gate rows {r,z,ni,nh} per channel; wave w owns
// channels 8w..8w+7 as 2 row-tiles. C/D layout (col=lane&15, row=lg*4+reg,
// HW-verified m89) puts all 4 gates of cell (b,ch) in one lane's 4 acc regs.
// Stage cols = 4 batch rows x 4 mirrors; each cell lives on 2 lanes
// (duplicate compute), each duplicate writes its 2 mirror cols.
// 2 barriers/step, deferred-store discipline: R1 reads stA/writes stC,
// R2 reads stC/writes stA; h0->stC(now)+stA(deferred); h1->stC(deferred);
// decoder x=h1->stA(now, in R2). Encoder phase A skips k<64 (x=0), gi0 from
// exact f32 rank-2 dense1 fold.

#define CCH  64
#define GG   192
#define SEQ  512
#define DECS 35
#define BT   4
#define NTH  512
#define NW   8
#define STG_SH (16 * 17 * 8)   // [kgroup 0..15][col 0..16 pad][8 elems] bf16

typedef __attribute__((ext_vector_type(8))) short bf16x8;
typedef __attribute__((ext_vector_type(4))) float f32x4;

__device__ __forceinline__ short f2b(float f) {   // f32 -> bf16 RNE
  union { float f; unsigned u; } v; v.f = f;
  unsigned r = v.u + 0x7fffu + ((v.u >> 16) & 1u);
  return (short)(r >> 16);
}
__device__ __forceinline__ float sigf(float x) { return 1.0f / (1.0f + __expf(-x)); }
__device__ __forceinline__ float tanhfast(float x) {
  float t = __expf(-2.0f * fabsf(x));
  float r = (1.0f - t) / (1.0f + t);
  return copysignf(r, x);
}
__device__ __forceinline__ int stoff(int col, int k) {  // stage elem index
  return ((k >> 3) * 17 + col) * 8 + (k & 7);
}

extern "C" __global__ void __launch_bounds__(NTH, 4)
gru_lane4(const float* __restrict__ pulse,   // [B,512,2]
          const float* __restrict__ d1w,     // [64,2]
          const float* __restrict__ d1b,     // [64]
          const float* __restrict__ d2w,     // [2,64]
          const float* __restrict__ d2b,     // [2]
          const float* __restrict__ Wih,     // [2,192,64]
          const float* __restrict__ Whh,     // [2,192,64]
          const float* __restrict__ bih,     // [2,192]
          const float* __restrict__ bhh,     // [2,192]
          const float* __restrict__ embed,   // [1,64]
          float* __restrict__ out)           // [B,35,2]
{
  __shared__ __align__(16) unsigned short stA[STG_SH];  // R1 operand [x | h0]
  __shared__ __align__(16) unsigned short stC[STG_SH];  // R2 operand [h0new | h1]
  __shared__ float red[NW * 8];                         // dense2 partials [w][b*2+o]

  const int tid = threadIdx.x;
  const int wid = tid >> 6;       // wave 0..7
  const int l   = tid & 63;
  const int lm  = l & 15;         // MFMA col / weight-row index
  const int lg  = l >> 4;         // k-group / acc quad
  const int b   = lm & 3;         // cell: batch row 0..3
  const int m   = lm >> 2;        // mirror 0..3
  const int tsel = m & 1;         // which row-tile holds this lane's cell
  const int ch  = wid * 8 + tsel * 4 + lg;   // cell: global channel
  const int wc0 = b + (m >> 1) * 8;          // this lane's 2 mirror cols
  const int wc1 = wc0 + 4;
  const int bgb = blockIdx.x * BT;

  for (int i = tid; i < STG_SH; i += NTH) { stA[i] = 0; stC[i] = 0; }

  // ---- weight A-fragments (held in VGPR all kernel); row map as round 8
  const float* Wih0 = Wih;
  const float* Whh0 = Whh;
  const float* Wih1 = Wih + GG * CCH;
  const float* Whh1 = Whh + GG * CCH;
  const int sub = lm & 3;          // 0=r 1=z 2=ni 3=nh
  bf16x8 bA[2][4], bC[2][4];
#pragma unroll
  for (int t = 0; t < 2; ++t) {
    const int wch = wid * 8 + t * 4 + (lm >> 2);   // channel of this weight row
    const int rr  = (sub == 0 ? wch : (sub == 1 ? 64 + wch : 128 + wch));
#pragma unroll
    for (int s = 0; s < 4; ++s) {
#pragma unroll
      for (int e = 0; e < 8; ++e) {
        int kk = 32 * s + 8 * lg + e;
        float va, vc;
        if (sub == 2) {        // n_i = [Wih_n | 0]
          va = kk < 64 ? Wih0[rr * CCH + kk] : 0.f;
          vc = kk < 64 ? Wih1[rr * CCH + kk] : 0.f;
        } else if (sub == 3) { // n_h = [0 | Whh_n]
          va = kk < 64 ? 0.f : Whh0[rr * CCH + kk - 64];
          vc = kk < 64 ? 0.f : Whh1[rr * CCH + kk - 64];
        } else {               // r,z = [Wih | Whh] full-K concat
          va = kk < 64 ? Wih0[rr * CCH + kk] : Whh0[rr * CCH + kk - 64];
          vc = kk < 64 ? Wih1[rr * CCH + kk] : Whh1[rr * CCH + kk - 64];
        }
        bA[t][s][e] = f2b(va);
        bC[t][s][e] = f2b(vc);
      }
    }
  }

  // ---- per-lane cell constants for channel ch
  float A0f[3], A1f[3], C0f[3];
#pragma unroll
  for (int g = 0; g < 3; ++g) {    // exact f32 dense1 fold (incl bih)
    int row = g * CCH + ch;
    float a0 = 0.f, a1 = 0.f, cc = 0.f;
    for (int k = 0; k < CCH; ++k) {
      float wv = Wih0[row * CCH + k];
      a0 += wv * d1w[2 * k];
      a1 += wv * d1w[2 * k + 1];
      cc += wv * d1b[k];
    }
    A0f[g] = a0; A1f[g] = a1; C0f[g] = cc + bih[row];
  }
  const float bh0r = bhh[ch], bh0z = bhh[64 + ch], bh0n = bhh[128 + ch];
  const float b0r = bih[ch] + bh0r, b0z = bih[64 + ch] + bh0z;
  const float bi0n = bih[128 + ch];
  const float b1r = bih[GG + ch] + bhh[GG + ch];
  const float b1z = bih[GG + 64 + ch] + bhh[GG + 64 + ch];
  const float bi1n = bih[GG + 128 + ch], bh1n = bhh[GG + 128 + ch];
  const float w2a = d2w[ch], w2b = d2w[CCH + ch];
  const float d2b0 = d2b[0], d2b1 = d2b[1];
  float h0 = 0.f, h1 = 0.f;
  short hb0 = 0, hb1 = 0;

  const float* prow = pulse + (size_t)(bgb + b) * SEQ * 2;
  __syncthreads();

  // ======================= encoder: 512 steps =======================
  for (int t = 0; t < SEQ; ++t) {
    // ---- R1: flush h1(t-1)->stC; gh0 MFMA (k-slices 2,3); lane-local L0 cell
    stC[stoff(wc0, 64 + ch)] = hb1;
    stC[stoff(wc1, 64 + ch)] = hb1;
    float2 pv = *(const float2*)(prow + 2 * t);
    f32x4 a0 = {0.f, 0.f, 0.f, 0.f}, a1 = {0.f, 0.f, 0.f, 0.f};
#pragma unroll
    for (int s = 2; s < 4; ++s) {
      bf16x8 af = *(const bf16x8*)&stA[((s * 4 + lg) * 17 + lm) * 8];
      a0 = __builtin_amdgcn_mfma_f32_16x16x32_bf16(bA[0][s], af, a0, 0, 0, 0);
      a1 = __builtin_amdgcn_mfma_f32_16x16x32_bf16(bA[1][s], af, a1, 0, 0, 0);
    }
    {
      f32x4 g = tsel ? a1 : a0;   // this lane's cell gates
      float fr = pv.x * A0f[0] + pv.y * A1f[0] + C0f[0];
      float fz = pv.x * A0f[1] + pv.y * A1f[1] + C0f[1];
      float fn = pv.x * A0f[2] + pv.y * A1f[2] + C0f[2];
      float r = sigf(fr + g[0] + bh0r);
      float z = sigf(fz + g[1] + bh0z);
      float nn = tanhfast(fn + r * (g[3] + bh0n));
      h0 = (1.f - z) * nn + z * h0;
      hb0 = f2b(h0);
      stC[stoff(wc0, ch)] = hb0;      // h0new -> R2 x-part (both mirror cols)
      stC[stoff(wc1, ch)] = hb0;
    }                                 // stA k>=64 write DEFERRED to R2
    __syncthreads();

    // ---- R2: flush h0(t)->stA; gi1+gh1 MFMA; lane-local L1 cell
    stA[stoff(wc0, 64 + ch)] = hb0;
    stA[stoff(wc1, 64 + ch)] = hb0;
    f32x4 c0 = {0.f, 0.f, 0.f, 0.f}, c1 = {0.f, 0.f, 0.f, 0.f};
#pragma unroll
    for (int s = 0; s < 4; ++s) {
      bf16x8 cf = *(const bf16x8*)&stC[((s * 4 + lg) * 17 + lm) * 8];
      c0 = __builtin_amdgcn_mfma_f32_16x16x32_bf16(bC[0][s], cf, c0, 0, 0, 0);
      c1 = __builtin_amdgcn_mfma_f32_16x16x32_bf16(bC[1][s], cf, c1, 0, 0, 0);
    }
    {
      f32x4 g = tsel ? c1 : c0;
      float r = sigf(g[0] + b1r);
      float z = sigf(g[1] + b1z);
      float nn = tanhfast(g[2] + bi1n + r * (g[3] + bh1n));
      h1 = (1.f - z) * nn + z * h1;
      hb1 = f2b(h1);                  // stC k>=64 DEFERRED to next R1
    }
    __syncthreads();
  }

  // ---- seed decoder input x = embed
  {
    short eb = f2b(embed[ch]);
    stA[stoff(wc0, ch)] = eb;
    stA[stoff(wc1, ch)] = eb;
  }
  __syncthreads();

  // ======================= decoder: 35 steps =======================
  for (int d = 0; d < DECS; ++d) {
    // ---- R1: flush h1(d-1)->stC; wave0 writes out(d-1); full-K MFMA; L0 cell
    stC[stoff(wc0, 64 + ch)] = hb1;
    stC[stoff(wc1, 64 + ch)] = hb1;
    if (wid == 0 && l < 8 && d > 0) {
      int bb = l >> 1, o = l & 1;
      float s = 0.f;
#pragma unroll
      for (int w = 0; w < NW; ++w) s += red[w * 8 + bb * 2 + o];
      out[((size_t)(bgb + bb) * DECS + (d - 1)) * 2 + o] = s + (o ? d2b1 : d2b0);
    }
    f32x4 a0 = {0.f, 0.f, 0.f, 0.f}, a1 = {0.f, 0.f, 0.f, 0.f};
#pragma unroll
    for (int s = 0; s < 4; ++s) {
      bf16x8 af = *(const bf16x8*)&stA[((s * 4 + lg) * 17 + lm) * 8];
      a0 = __builtin_amdgcn_mfma_f32_16x16x32_bf16(bA[0][s], af, a0, 0, 0, 0);
      a1 = __builtin_amdgcn_mfma_f32_16x16x32_bf16(bA[1][s], af, a1, 0, 0, 0);
    }
    {
      f32x4 g = tsel ? a1 : a0;   // reg0 = gi_r+gh_r (summed inside MFMA)
      float r = sigf(g[0] + b0r);
      float z = sigf(g[1] + b0z);
      float nn = tanhfast(g[2] + bi0n + r * (g[3] + bh0n));
      h0 = (1.f - z) * nn + z * h0;
      hb0 = f2b(h0);
      stC[stoff(wc0, ch)] = hb0;
      stC[stoff(wc1, ch)] = hb0;
    }
    __syncthreads();

    // ---- R2: flush h0(d)->stA; MFMA; L1 cell + x-store + dense2 partial
    stA[stoff(wc0, 64 + ch)] = hb0;
    stA[stoff(wc1, 64 + ch)] = hb0;
    f32x4 c0 = {0.f, 0.f, 0.f, 0.f}, c1 = {0.f, 0.f, 0.f, 0.f};
#pragma unroll
    for (int s = 0; s < 4; ++s) {
      bf16x8 cf = *(const bf16x8*)&stC[((s * 4 + lg) * 17 + lm) * 8];
      c0 = __builtin_amdgcn_mfma_f32_16x16x32_bf16(bC[0][s], cf, c0, 0, 0, 0);
      c1 = __builtin_amdgcn_mfma_f32_16x16x32_bf16(bC[1][s], cf, c1, 0, 0, 0);
    }
    {
      f32x4 g = tsel ? c1 : c0;
      float r = sigf(g[0] + b1r);
      float z = sigf(g[1] + b1z);
      float nn = tanhfast(g[2] + bi1n + r * (g[3] + bh1n));
      h1 = (1.f - z) * nn + z * h1;
      hb1 = f2b(h1);                  // stC k>=64 DEFERRED to next R1
      stA[stoff(wc0, ch)] = hb1;      // x(d+1) (R1 reads after barrier)
      stA[stoff(wc1, ch)] = hb1;
      // dense2 partial: sum over channels = {tsel (xor 4), lg (xor 16,32)};
      // xor 8 would add the duplicate copy, so skip it.
      float p0 = h1 * w2a, p1 = h1 * w2b;
      p0 += __shfl_xor(p0, 4);  p1 += __shfl_xor(p1, 4);
      p0 += __shfl_xor(p0, 16); p1 += __shfl_xor(p1, 16);
      p0 += __shfl_xor(p0, 32); p1 += __shfl_xor(p1, 32);
      if (l < 4) {                    // lane l: b=l, m=0, lg=0
        red[wid * 8 + b * 2 + 0] = p0;
        red[wid * 8 + b * 2 + 1] = p1;
      }
    }
    __syncthreads();
  }

  // ---- final output flush (d = 34)
  if (wid == 0 && l < 8) {
    int bb = l >> 1, o = l & 1;
    float s = 0.f;
#pragma unroll
    for (int w = 0; w < NW; ++w) s += red[w * 8 + bb * 2 + o];
    out[((size_t)(bgb + bb) * DECS + (DECS - 1)) * 2 + o] = s + (o ? d2b1 : d2b0);
  }
}

extern "C" void kernel_launch(void* const* d_in, const int* in_sizes, int n_in,
                              void* d_out, int out_size, void* d_ws, size_t ws_size,
                              hipStream_t stream) {
  const float* pulse = (const float*)d_in[0];
  const float* d1w   = (const float*)d_in[1];
  const float* d1b   = (const float*)d_in[2];
  const float* d2w   = (const float*)d_in[3];
  const float* d2b   = (const float*)d_in[4];
  const float* Wih   = (const float*)d_in[5];
  const float* Whh   = (const float*)d_in[6];
  const float* bih   = (const float*)d_in[7];
  const float* bhh   = (const float*)d_in[8];
  const float* emb   = (const float*)d_in[9];
  float* out = (float*)d_out;

  int B = in_sizes[0] / (SEQ * 2);   // 2048
  gru_lane4<<<B / BT, NTH, 0, stream>>>(pulse, d1w, d1b, d2w, d2b,
                                        Wih, Whh, bih, bhh, emb, out);
}

// Round 11
// 769.133 us; speedup vs baseline: 1.1217x; 1.1217x over previous
//
#include <hip/hip_runtime.h>
#include <math.h>

// GRU C=64, L=2, B=2048, SEQ=512, DEC=35. BT=8 rows/block, grid=256 (1/CU).
// 512 threads = 8 waves, WAVE-SPECIALIZED LAYER PIPELINE:
//   waves 0-3 = layer-0 group (4 N-tiles each = 16 channels each)
//   waves 4-7 = layer-1 group (same tiling for layer 1)
// Encoder iteration i (ONE barrier): L0-waves compute h0(i) from h0(i-1);
// L1-waves concurrently compute h1(i-1) from [h0(i-1); h1(i-2)] -> 512 regions
// instead of 1024. Decoder can't pipeline (h0(d) needs h1(d-1)): 2 regions/step,
// idle group forwards its held state (covers all lag-2 reads).
//
// Stages double-buffered by region parity p: ALL reads from buf[p], ALL writes
// to buf[p^1] -> race-free by construction. stA = [x | h0] (L0 operand),
// stC = [h0 | h1] (L1 operand), bf16.
//
// LANE-LOCAL CELLS (round-8 verified): G[gates][batch] = W(K=128)·[x;h] with
// weights as MFMA A-operand (VGPR-resident bf16 whole kernel). Gate rows per
// channel {r,z,ni,nh} (r,z = full-K concat -> MFMA emits gi+gh; n split).
// C/D: col=lane&15, row=(lane>>4)*4+reg (HW-verified m89) -> lane's 4 acc regs
// of tile t = all 4 gates of cell (b=lm&7, ch=base+4t+lg); 4 cells/lane.
// Encoder L0 skips k<64 slices (x-block zero; gi0 via exact f32 dense1 fold).

#define CCH  64
#define GG   192
#define SEQ  512
#define DECS 35
#define BT   8
#define NTH  512
#define STG_SH (16 * 17 * 8)   // [kgroup 0..15][col 0..16 pad][8 elems] bf16

typedef __attribute__((ext_vector_type(8))) short bf16x8;
typedef __attribute__((ext_vector_type(4))) float f32x4;

__device__ __forceinline__ short f2b(float f) {   // f32 -> bf16 RNE
  union { float f; unsigned u; } v; v.f = f;
  unsigned r = v.u + 0x7fffu + ((v.u >> 16) & 1u);
  return (short)(r >> 16);
}
__device__ __forceinline__ float sigf(float x) { return 1.0f / (1.0f + __expf(-x)); }
__device__ __forceinline__ float tanhfast(float x) {
  float t = __expf(-2.0f * fabsf(x));
  float r = (1.0f - t) / (1.0f + t);
  return copysignf(r, x);
}
__device__ __forceinline__ int stoff(int col, int k) {  // stage elem index
  return ((k >> 3) * 17 + col) * 8 + (k & 7);
}

extern "C" __global__ void __launch_bounds__(NTH, 2)
gru_pipe(const float* __restrict__ pulse,   // [B,512,2]
         const float* __restrict__ d1w,     // [64,2]
         const float* __restrict__ d1b,     // [64]
         const float* __restrict__ d2w,     // [2,64]
         const float* __restrict__ d2b,     // [2]
         const float* __restrict__ Wih,     // [2,192,64]
         const float* __restrict__ Whh,     // [2,192,64]
         const float* __restrict__ bih,     // [2,192]
         const float* __restrict__ bhh,     // [2,192]
         const float* __restrict__ embed,   // [1,64]
         float* __restrict__ out)           // [B,35,2]
{
  __shared__ __align__(16) unsigned short stA[2][STG_SH];  // L0 operand [x | h0]
  __shared__ __align__(16) unsigned short stC[2][STG_SH];  // L1 operand [h0 | h1]
  __shared__ float red[4 * 8 * 2];                         // dense2 partials

  const int tid  = threadIdx.x;
  const int wid  = tid >> 6;
  const int l    = tid & 63;
  const int role = wid >> 2;        // 0 = layer0 group, 1 = layer1 group
  const int wq   = wid & 3;
  const int base = wq * 16;         // first channel of this wave
  const int lm   = l & 15;          // MFMA row-lane (A) / col (B,C)
  const int lg   = l >> 4;          // k-group / acc quad
  const int b    = lm & 7;          // cell batch row
  const int col  = lm;              // stage col this lane writes (b + 8*mirror)
  const int bgb  = blockIdx.x * BT;

  for (int i = tid; i < STG_SH; i += NTH) {
    stA[0][i] = 0; stA[1][i] = 0; stC[0][i] = 0; stC[1][i] = 0;
  }

  // ---- weight A-fragments for this role's layer (VGPR, whole kernel)
  const float* WihL = Wih + role * GG * CCH;
  const float* WhhL = Whh + role * GG * CCH;
  const int sub = lm & 3;          // 0=r 1=z 2=ni 3=nh
  bf16x8 bW[4][4];
#pragma unroll
  for (int t = 0; t < 4; ++t) {
    const int wch = base + t * 4 + (lm >> 2);
    const int rr  = (sub == 0 ? wch : (sub == 1 ? 64 + wch : 128 + wch));
#pragma unroll
    for (int s = 0; s < 4; ++s) {
#pragma unroll
      for (int e = 0; e < 8; ++e) {
        int kk = 32 * s + 8 * lg + e;
        float v;
        if (sub == 2)      v = kk < 64 ? WihL[rr * CCH + kk] : 0.f;        // [Wih_n|0]
        else if (sub == 3) v = kk < 64 ? 0.f : WhhL[rr * CCH + kk - 64];   // [0|Whh_n]
        else               v = kk < 64 ? WihL[rr * CCH + kk]
                                       : WhhL[rr * CCH + kk - 64];         // [Wih|Whh]
        bW[t][s][e] = f2b(v);
      }
    }
  }

  // ---- per-lane cell constants; cell t: channel chc[t] = base + 4t + lg
  int chc[4];
#pragma unroll
  for (int t = 0; t < 4; ++t) chc[t] = base + t * 4 + lg;

  float A0f[4][3], A1f[4][3], C0f[4][3];               // L0: exact dense1 fold
  float cR[4], cZ[4], ciN[4], chN[4];                  // role-dependent biases
  float w2a[4], w2b[4];
  if (!role) {
#pragma unroll
    for (int t = 0; t < 4; ++t) {
      int ch = chc[t];
#pragma unroll
      for (int g = 0; g < 3; ++g) {
        int row = g * CCH + ch;
        float a0 = 0.f, a1 = 0.f, cc = 0.f;
        for (int k = 0; k < CCH; ++k) {
          float wv = Wih[row * CCH + k];
          a0 += wv * d1w[2 * k];
          a1 += wv * d1w[2 * k + 1];
          cc += wv * d1b[k];
        }
        A0f[t][g] = a0; A1f[t][g] = a1; C0f[t][g] = cc + bih[row];
      }
      cR[t]  = bih[ch] + bhh[ch];                 // decoder r bias (gi+gh summed)
      cZ[t]  = bih[64 + ch] + bhh[64 + ch];
      ciN[t] = bih[128 + ch];
      chN[t] = bhh[128 + ch];
      // encoder also needs bhh alone (fold covers bih):
      w2a[t] = bhh[ch];        // reuse: enc r  bhh
      w2b[t] = bhh[64 + ch];   // reuse: enc z  bhh
    }
  } else {
#pragma unroll
    for (int t = 0; t < 4; ++t) {
      int ch = chc[t];
      cR[t]  = bih[GG + ch] + bhh[GG + ch];
      cZ[t]  = bih[GG + 64 + ch] + bhh[GG + 64 + ch];
      ciN[t] = bih[GG + 128 + ch];
      chN[t] = bhh[GG + 128 + ch];
      w2a[t] = d2w[ch]; w2b[t] = d2w[CCH + ch];
    }
  }
  const float d2b0 = d2b[0], d2b1 = d2b[1];

  // seed embed into both stA buffers' x-part (constant through encoder)
  if (!role) {
#pragma unroll
    for (int t = 0; t < 4; ++t) {
      short eb = f2b(embed[chc[t]]);
      stA[0][stoff(col, chc[t])] = eb;
      stA[1][stoff(col, chc[t])] = eb;
    }
  }

  float h[4] = {0.f, 0.f, 0.f, 0.f};
  short hbv[4] = {0, 0, 0, 0};
  __syncthreads();
  int p = 0;

  // ======================= encoder: 512 regions =======================
  const float* prow = pulse + (size_t)(bgb + b) * SEQ * 2;
  float2 pv = role ? make_float2(0.f, 0.f) : *(const float2*)(prow);
  for (int t = 0; t < SEQ; ++t) {
    if (!role) {
      float2 pnx = pv;
      if (t + 1 < SEQ) pnx = *(const float2*)(prow + 2 * (t + 1));
      f32x4 acc[4] = {{0,0,0,0},{0,0,0,0},{0,0,0,0},{0,0,0,0}};
#pragma unroll
      for (int s = 2; s < 4; ++s) {          // h0-part only (x-block = fold)
        bf16x8 af = *(const bf16x8*)&stA[p][((s * 4 + lg) * 17 + lm) * 8];
#pragma unroll
        for (int q = 0; q < 4; ++q)
          acc[q] = __builtin_amdgcn_mfma_f32_16x16x32_bf16(bW[q][s], af, acc[q], 0, 0, 0);
      }
#pragma unroll
      for (int q = 0; q < 4; ++q) {
        f32x4 g = acc[q];
        float fr = pv.x * A0f[q][0] + pv.y * A1f[q][0] + C0f[q][0];
        float fz = pv.x * A0f[q][1] + pv.y * A1f[q][1] + C0f[q][1];
        float fn = pv.x * A0f[q][2] + pv.y * A1f[q][2] + C0f[q][2];
        float r = sigf(fr + g[0] + w2a[q]);          // w2a = bhh_r (L0 reuse)
        float z = sigf(fz + g[1] + w2b[q]);          // w2b = bhh_z
        float nn = tanhfast(fn + r * (g[3] + chN[q]));
        h[q] = (1.f - z) * nn + z * h[q];
        hbv[q] = f2b(h[q]);
        stA[p ^ 1][stoff(col, 64 + chc[q])] = hbv[q];
        stC[p ^ 1][stoff(col, chc[q])]      = hbv[q];
      }
      pv = pnx;
    } else if (t > 0) {                      // L1: compute h1(t-1)
      f32x4 acc[4] = {{0,0,0,0},{0,0,0,0},{0,0,0,0},{0,0,0,0}};
#pragma unroll
      for (int s = 0; s < 4; ++s) {
        bf16x8 af = *(const bf16x8*)&stC[p][((s * 4 + lg) * 17 + lm) * 8];
#pragma unroll
        for (int q = 0; q < 4; ++q)
          acc[q] = __builtin_amdgcn_mfma_f32_16x16x32_bf16(bW[q][s], af, acc[q], 0, 0, 0);
      }
#pragma unroll
      for (int q = 0; q < 4; ++q) {
        f32x4 g = acc[q];
        float r = sigf(g[0] + cR[q]);
        float z = sigf(g[1] + cZ[q]);
        float nn = tanhfast(g[2] + ciN[q] + r * (g[3] + chN[q]));
        h[q] = (1.f - z) * nn + z * h[q];
        hbv[q] = f2b(h[q]);
        stC[p ^ 1][stoff(col, 64 + chc[q])] = hbv[q];
      }
    }
    __syncthreads();
    p ^= 1;
  }

  // ===== transition: L0 -> h0(dec0) (full-K, x=embed); L1 -> h1(511) =====
  {
    f32x4 acc[4] = {{0,0,0,0},{0,0,0,0},{0,0,0,0},{0,0,0,0}};
    const unsigned short* SB = role ? stC[p] : stA[p];
#pragma unroll
    for (int s = 0; s < 4; ++s) {
      bf16x8 af = *(const bf16x8*)&SB[((s * 4 + lg) * 17 + lm) * 8];
#pragma unroll
      for (int q = 0; q < 4; ++q)
        acc[q] = __builtin_amdgcn_mfma_f32_16x16x32_bf16(bW[q][s], af, acc[q], 0, 0, 0);
    }
#pragma unroll
    for (int q = 0; q < 4; ++q) {
      f32x4 g = acc[q];
      float r = sigf(g[0] + cR[q]);
      float z = sigf(g[1] + cZ[q]);
      float nn = tanhfast(g[2] + ciN[q] + r * (g[3] + chN[q]));
      h[q] = (1.f - z) * nn + z * h[q];
      hbv[q] = f2b(h[q]);
      if (!role) {
        stA[p ^ 1][stoff(col, 64 + chc[q])] = hbv[q];
        stC[p ^ 1][stoff(col, chc[q])]      = hbv[q];
      } else {
        stC[p ^ 1][stoff(col, 64 + chc[q])] = hbv[q];
      }
    }
    __syncthreads();
    p ^= 1;
  }

  // ======================= decoder: 2 regions/step =======================
  for (int d = 0; d < DECS; ++d) {
    // ---- regionB: L1 active -> h1(d); L0 forwards h0(d)
    if (role) {
      f32x4 acc[4] = {{0,0,0,0},{0,0,0,0},{0,0,0,0},{0,0,0,0}};
#pragma unroll
      for (int s = 0; s < 4; ++s) {
        bf16x8 af = *(const bf16x8*)&stC[p][((s * 4 + lg) * 17 + lm) * 8];
#pragma unroll
        for (int q = 0; q < 4; ++q)
          acc[q] = __builtin_amdgcn_mfma_f32_16x16x32_bf16(bW[q][s], af, acc[q], 0, 0, 0);
      }
      float p0 = 0.f, p1 = 0.f;
#pragma unroll
      for (int q = 0; q < 4; ++q) {
        f32x4 g = acc[q];
        float r = sigf(g[0] + cR[q]);
        float z = sigf(g[1] + cZ[q]);
        float nn = tanhfast(g[2] + ciN[q] + r * (g[3] + chN[q]));
        h[q] = (1.f - z) * nn + z * h[q];
        hbv[q] = f2b(h[q]);
        stC[p ^ 1][stoff(col, 64 + chc[q])] = hbv[q];   // h1 for next regionB
        stA[p ^ 1][stoff(col, chc[q])]      = hbv[q];   // x for next regionA
        p0 += h[q] * w2a[q];
        p1 += h[q] * w2b[q];
      }
      p0 += __shfl_xor(p0, 16); p0 += __shfl_xor(p0, 32);
      p1 += __shfl_xor(p1, 16); p1 += __shfl_xor(p1, 32);
      if (l < 8) {
        red[((wid - 4) * 8 + b) * 2 + 0] = p0;
        red[((wid - 4) * 8 + b) * 2 + 1] = p1;
      }
    } else {
#pragma unroll
      for (int q = 0; q < 4; ++q)                        // forward h0(d)
        stA[p ^ 1][stoff(col, 64 + chc[q])] = hbv[q];
    }
    __syncthreads();
    p ^= 1;

    // ---- regionA: L0 active -> h0(d+1); L1 forwards h1(d) + writes out(d)
    if (!role) {
      if (d < DECS - 1) {
        f32x4 acc[4] = {{0,0,0,0},{0,0,0,0},{0,0,0,0},{0,0,0,0}};
#pragma unroll
        for (int s = 0; s < 4; ++s) {
          bf16x8 af = *(const bf16x8*)&stA[p][((s * 4 + lg) * 17 + lm) * 8];
#pragma unroll
          for (int q = 0; q < 4; ++q)
            acc[q] = __builtin_amdgcn_mfma_f32_16x16x32_bf16(bW[q][s], af, acc[q], 0, 0, 0);
        }
#pragma unroll
        for (int q = 0; q < 4; ++q) {
          f32x4 g = acc[q];
          float r = sigf(g[0] + cR[q]);
          float z = sigf(g[1] + cZ[q]);
          float nn = tanhfast(g[2] + ciN[q] + r * (g[3] + chN[q]));
          h[q] = (1.f - z) * nn + z * h[q];
          hbv[q] = f2b(h[q]);
          stA[p ^ 1][stoff(col, 64 + chc[q])] = hbv[q];
          stC[p ^ 1][stoff(col, chc[q])]      = hbv[q];
        }
      }
    } else {
#pragma unroll
      for (int q = 0; q < 4; ++q)                        // forward h1(d)
        stC[p ^ 1][stoff(col, 64 + chc[q])] = hbv[q];
      if (wid == 4 && l < 16) {
        int bb = l >> 1, o = l & 1;
        float s_ = red[(0 * 8 + bb) * 2 + o] + red[(1 * 8 + bb) * 2 + o]
                 + red[(2 * 8 + bb) * 2 + o] + red[(3 * 8 + bb) * 2 + o];
        out[((size_t)(bgb + bb) * DECS + d) * 2 + o] = s_ + (o ? d2b1 : d2b0);
      }
    }
    __syncthreads();
    p ^= 1;
  }
}

extern "C" void kernel_launch(void* const* d_in, const int* in_sizes, int n_in,
                              void* d_out, int out_size, void* d_ws, size_t ws_size,
                              hipStream_t stream) {
  const float* pulse = (const float*)d_in[0];
  const float* d1w   = (const float*)d_in[1];
  const float* d1b   = (const float*)d_in[2];
  const float* d2w   = (const float*)d_in[3];
  const float* d2b   = (const float*)d_in[4];
  const float* Wih   = (const float*)d_in[5];
  const float* Whh   = (const float*)d_in[6];
  const float* bih   = (const float*)d_in[7];
  const float* bhh   = (const float*)d_in[8];
  const float* emb   = (const float*)d_in[9];
  float* out = (float*)d_out;

  int B = in_sizes[0] / (SEQ * 2);   // 2048
  gru_pipe<<<B / BT, NTH, 0, stream>>>(pulse, d1w, d1b, d2w, d2b,
                                       Wih, Whh, bih, bhh, emb, out);
}